// Round 18
// baseline (64.643 us; speedup 1.0000x reference)
//
#include <hip/hip_runtime.h>
#include <hip/hip_bf16.h>

#define B_    4096
#define D_    512         // elements = bytes per row (i8)
#define TB_   8192        // 2B rows
#define BM    128
#define BK    128         // 128 B per row per K-tile (0-conflict geometry)
#define NK    4           // D_/BK
#define NTILE 64          // TB_/BM
#define NTRI  2080        // NTILE*(NTILE+1)/2 = 8*260 (XCD-bijective)
#define INV_T 14.285714285714286f   // 1/0.07
#define SCL   (INV_T / 16129.0f)    // 1/(0.07*127*127)

typedef __attribute__((ext_vector_type(4))) int v4i;

#define GLOAD_LDS16(gp, lp)                                                        \
  __builtin_amdgcn_global_load_lds((const __attribute__((address_space(1))) void*)(gp), \
                                   (__attribute__((address_space(3))) void*)(lp),  \
                                   16, 0, 0)

// ---------------------------------------------------------------------------
// Kernel 1: concat + quantize fp32 -> int8 (E8[8192][512], q = rn(127 x)).
// ---------------------------------------------------------------------------
__global__ void ntx_prep(const float* __restrict__ a, const float* __restrict__ b,
                         char* __restrict__ E8) {
  int t = blockIdx.x * blockDim.x + threadIdx.x;      // 0..262143
  int i = t * 16;
  const float* src = (i < B_ * D_) ? (a + i) : (b + (i - B_ * D_));
  v4i o;
#pragma unroll
  for (int g = 0; g < 4; ++g) {
    float4 v = ((const float4*)src)[g];
    int q0 = __float2int_rn(v.x * 127.0f) & 255;
    int q1 = __float2int_rn(v.y * 127.0f) & 255;
    int q2 = __float2int_rn(v.z * 127.0f) & 255;
    int q3 = __float2int_rn(v.w * 127.0f) & 255;
    o[g] = q0 | (q1 << 8) | (q2 << 16) | (q3 << 24);
  }
  ((v4i*)E8)[t] = o;
}

// ---------------------------------------------------------------------------
// Kernel 2: HYBRID operand sourcing to halve LDS-bank traffic (the newly
// identified floor: 1.07 GB ds_read @ ~52 TB/s/CU-aggregate ~ 22 us):
//   A: staged in LDS exactly as R17 (gload_lds, chunk-XOR both sides).
//   B: loaded DIRECTLY global->VGPR per wave (no LDS write, no ds_read).
//      Frag addr (from the verified involution, swizzle cancels):
//      E8[(colTile+wc*64+m*16+llo)*512 + kt*128 + ks*64 + lhi*16].
//      Issued at iter top, before the A-drain barrier -> L2 latency hides
//      under the drain that already waits for A.
// LDS traffic: reads 1.07 GB -> 537 MB, writes 266 -> 133 MB.
// Everything else identical to R17 (passed, 50.1 us).
// ---------------------------------------------------------------------------
__global__ __launch_bounds__(256, 2)
void ntx_sim(const char* __restrict__ E8, float* __restrict__ P,
             float* __restrict__ pos) {
  __shared__ __align__(16) char As[BM * BK];   // 16 KB (A only)

  // XCD-contiguous bijective swizzle (2080 = 8*260)
  const int bid = blockIdx.x;
  const int t   = (bid & 7) * (NTRI / 8) + (bid >> 3);
  // decode triangular index t -> (ti, tj), ti<=tj
  int ti = (int)((129.0f - sqrtf(16641.0f - 8.0f * (float)t)) * 0.5f);
  while (ti * (129 - ti) / 2 > t) --ti;
  while ((ti + 1) * (128 - ti) / 2 <= t) ++ti;
  const int tj = ti + (t - ti * (129 - ti) / 2);
  const int rowTile = ti * BM, colTile = tj * BM;
  const bool diag = (ti == tj);
  const bool posT = (tj == ti + B_ / BM);   // holds s[r][r+B] on local diag

  const int tid = threadIdx.x, lane = tid & 63, wave = tid >> 6;
  const int wr = wave >> 1, wc = wave & 1;
  const int llo = lane & 15, lhi = lane >> 4;

  // --- A staging bases (R17 diet): round r adds r*16384 / r*4096 ---
  const int srow = tid >> 3;
  const int ssc  = ((tid & 7) ^ (srow & 7)) << 4;
  const unsigned offA0  = (unsigned)(rowTile + srow) * D_ + ssc;
  const unsigned ldsOf0 = (unsigned)tid * 16;

  // --- A fragment base: fA[ks][m] = baseA ^ (ks*64) + m*2048 ---
  const unsigned baseA = (unsigned)((wr * 64 + llo) * BK + ((lhi ^ (llo & 7)) << 4));

  // --- B direct-global per-lane offsets (4 VGPRs) ---
  unsigned bOff[4];
#pragma unroll
  for (int m = 0; m < 4; ++m)
    bOff[m] = (unsigned)(colTile + wc * 64 + m * 16 + llo) * D_ + lhi * 16;

  v4i acc[4][4] = {};

  for (int kt = 0; kt < NK; ++kt) {
    const unsigned kb = (unsigned)kt * BK;
    // 1) issue B fragment loads (global -> VGPR), both ks halves
    v4i bf0[4], bf1[4];
#pragma unroll
    for (int m = 0; m < 4; ++m) bf0[m] = *(const v4i*)(E8 + bOff[m] + kb);
#pragma unroll
    for (int m = 0; m < 4; ++m) bf1[m] = *(const v4i*)(E8 + bOff[m] + kb + 64);
    // 2) stage A tile kt into LDS
#pragma unroll
    for (int r = 0; r < 4; ++r)
      GLOAD_LDS16(E8 + offA0 + r * 16384 + kb, &As[ldsOf0 + r * 4096]);
    __syncthreads();   // drains vmcnt: A resident (B regs filled by then too)
    // 3) compute
#pragma unroll
    for (int ks = 0; ks < 2; ++ks) {
      const unsigned bA = baseA ^ (ks * 64);
      v4i af[4];
#pragma unroll
      for (int m = 0; m < 4; ++m) af[m] = *(const v4i*)&As[bA + m * 2048];
#pragma unroll
      for (int m = 0; m < 4; ++m)
#pragma unroll
        for (int n = 0; n < 4; ++n)
          acc[m][n] = __builtin_amdgcn_mfma_i32_16x16x64_i8(
              af[m], (ks ? bf1 : bf0)[n], acc[m][n], 0, 0, 0);
    }
    __syncthreads();   // protect As before next staging
  }

  // --- epilogue (R13/R17-verified): exp, partials, single-writer P stores ---
  // C/D layout: col = lane&15, row = (lane>>4)*4 + reg
  float* __restrict__ Prow = P + ((size_t)ti * 2 * NTILE + (size_t)tj * 2 + wc) * BM;
  float* __restrict__ Pcol = P + ((size_t)tj * 2 * NTILE + (size_t)ti * 2 + wr) * BM;
  float cs[4] = {0.f, 0.f, 0.f, 0.f};
#pragma unroll
  for (int m = 0; m < 4; ++m) {
    float rs[4] = {0.f, 0.f, 0.f, 0.f};
#pragma unroll
    for (int n = 0; n < 4; ++n) {
      int gc = colTile + wc * 64 + n * 16 + llo;
#pragma unroll
      for (int jj = 0; jj < 4; ++jj) {
        int gr = rowTile + wr * 64 + m * 16 + lhi * 4 + jj;
        float s = (float)acc[m][n][jj] * SCL;
        if (posT && gc - gr == B_) pos[gr] = s;   // unique writer
        float e = __expf(s);
        e = (diag && gr == gc) ? 0.0f : e;
        rs[jj] += e;
        cs[n]  += e;
      }
    }
#pragma unroll
    for (int jj = 0; jj < 4; ++jj) {
      float v = rs[jj];
      v += __shfl_xor(v, 1);
      v += __shfl_xor(v, 2);
      v += __shfl_xor(v, 4);
      v += __shfl_xor(v, 8);
      if (llo == 0) Prow[wr * 64 + m * 16 + lhi * 4 + jj] = v;  // slot tj*2+wc
    }
  }
  if (!diag) {
    // column sums = row sums of mirrored tile (j,i)
#pragma unroll
    for (int n = 0; n < 4; ++n) {
      float v = cs[n];
      v += __shfl_xor(v, 16);
      v += __shfl_xor(v, 32);
      if (lhi == 0) Pcol[wc * 64 + n * 16 + llo] = v;           // slot ti*2+wr
    }
  }
}

// ---------------------------------------------------------------------------
// Kernel 3: gather L[r] = sum over 128 slots of P[ti][j2][rloc];
// nll = log(L) - pos; per-block partial -> par[32].
// ---------------------------------------------------------------------------
__global__ void ntx_fin1(const float* __restrict__ P, const float* __restrict__ pos,
                         float* __restrict__ par) {
  int r = blockIdx.x * 256 + threadIdx.x;     // 32 blocks x 256 rows
  int ti = r >> 7, rloc = r & 127;
  const float* base = P + (size_t)ti * 2 * NTILE * BM + rloc;
  float s = 0.f;
#pragma unroll 16
  for (int j = 0; j < 2 * NTILE; ++j) s += base[j * BM];
  float nll = __logf(s) - pos[r & (B_ - 1)];
  float v = nll;
#pragma unroll
  for (int off = 1; off < 64; off <<= 1) v += __shfl_xor(v, off);
  __shared__ float sm[4];
  if ((threadIdx.x & 63) == 0) sm[threadIdx.x >> 6] = v;
  __syncthreads();
  if (threadIdx.x == 0) par[blockIdx.x] = sm[0] + sm[1] + sm[2] + sm[3];
}

// Kernel 4: fold 32 partials -> mean
__global__ void ntx_fin2(const float* __restrict__ par, float* __restrict__ out) {
  int t = threadIdx.x;                         // 64 threads
  float s = (t < 32) ? par[t] : 0.f;
#pragma unroll
  for (int off = 1; off < 32; off <<= 1) s += __shfl_xor(s, off);
  if (t == 0) out[0] = s * (1.0f / TB_);
}

// ---------------------------------------------------------------------------
extern "C" void kernel_launch(void* const* d_in, const int* in_sizes, int n_in,
                              void* d_out, int out_size, void* d_ws, size_t ws_size,
                              hipStream_t stream) {
  const float* e1 = (const float*)d_in[0];
  const float* e2 = (const float*)d_in[1];
  float* out = (float*)d_out;
  char*  E8  = (char*)d_ws;                                       // 4 MB i8
  float* P   = (float*)((char*)d_ws + (size_t)TB_ * D_);          // 4 MB partials
  float* pos = P + (size_t)NTILE * 2 * NTILE * BM;                // 16 KB
  float* par = pos + B_;                                          // 128 B

  ntx_prep<<<1024, 256, 0, stream>>>(e1, e2, E8);
  ntx_sim<<<NTRI, 256, 0, stream>>>(E8, P, pos);
  ntx_fin1<<<TB_ / 256, 256, 0, stream>>>(P, pos, par);
  ntx_fin2<<<1, 64, 0, stream>>>(par, out);
}

// Round 19
// 56.984 us; speedup vs baseline: 1.1344x; 1.1344x over previous
//
#include <hip/hip_runtime.h>
#include <hip/hip_bf16.h>

#define B_    4096
#define D_    512         // elements = bytes per row (i8)
#define TB_   8192        // 2B rows
#define BM    128
#define BK    128         // 128 B per row per K-tile (0-conflict geometry)
#define NK    4           // D_/BK
#define NTILE 64          // TB_/BM
#define NTRI  2080        // triangular tiles
#define NPAIR 1040        // NTRI/2 = 8*130 (XCD-bijective)
#define INV_T 14.285714285714286f   // 1/0.07
#define SCL   (INV_T / 16129.0f)    // 1/(0.07*127*127)

typedef __attribute__((ext_vector_type(4))) int v4i;

#define GLOAD_LDS16(gp, lp)                                                        \
  __builtin_amdgcn_global_load_lds((const __attribute__((address_space(1))) void*)(gp), \
                                   (__attribute__((address_space(3))) void*)(lp),  \
                                   16, 0, 0)

__device__ __forceinline__ void tri_decode(int u, int& ti, int& tj) {
  int i = (int)((129.0f - sqrtf(16641.0f - 8.0f * (float)u)) * 0.5f);
  while (i * (129 - i) / 2 > u) --i;
  while ((i + 1) * (128 - i) / 2 <= u) ++i;
  ti = i;
  tj = i + (u - i * (129 - i) / 2);
}

// ---------------------------------------------------------------------------
// Kernel 1: concat + quantize fp32 -> int8 (E8[8192][512], q = rn(127 x)).
// ---------------------------------------------------------------------------
__global__ void ntx_prep(const float* __restrict__ a, const float* __restrict__ b,
                         char* __restrict__ E8) {
  int t = blockIdx.x * blockDim.x + threadIdx.x;      // 0..262143
  int i = t * 16;
  const float* src = (i < B_ * D_) ? (a + i) : (b + (i - B_ * D_));
  v4i o;
#pragma unroll
  for (int g = 0; g < 4; ++g) {
    float4 v = ((const float4*)src)[g];
    int q0 = __float2int_rn(v.x * 127.0f) & 255;
    int q1 = __float2int_rn(v.y * 127.0f) & 255;
    int q2 = __float2int_rn(v.z * 127.0f) & 255;
    int q3 = __float2int_rn(v.w * 127.0f) & 255;
    o[g] = q0 | (q1 << 8) | (q2 << 16) | (q3 << 24);
  }
  ((v4i*)E8)[t] = o;
}

// ---------------------------------------------------------------------------
// Kernel 2: PAIRED-TILE i8 GEMM. Block = triangular tiles (2t, 2t+1) —
// usually same ti (A shared); ~63 row-crossing pairs stage a second A.
// 8 waves: waves 0-3 -> tile0, 4-7 -> tile1, each half is exactly R13's
// proven 4-wave 2x2 structure. Per kt: ONE barrier-pair covers TWO tiles
// of MFMA -> drain events halved (8320 -> 4160) and rounds 4.06 -> 2.03.
// LDS 64 KB (A0,A1,B0,B1) -> 2 blocks/CU, 16 waves/CU.
// Chunk-XOR swizzle on BOTH source and ds_read (0-conflict, verified).
// Atomic-free epilogue (R13-verified): single-writer P slots per half.
// ---------------------------------------------------------------------------
__global__ __launch_bounds__(512, 4)
void ntx_sim(const char* __restrict__ E8, float* __restrict__ P,
             float* __restrict__ pos) {
  __shared__ __align__(16) char As[2][BM * BK];   // 32 KB
  __shared__ __align__(16) char Bs[2][BM * BK];   // 32 KB

  // XCD-contiguous bijective swizzle (1040 = 8*130)
  const int bid = blockIdx.x;
  const int pt  = (bid & 7) * (NPAIR / 8) + (bid >> 3);
  int ti0, tj0, ti1, tj1;
  tri_decode(2 * pt,     ti0, tj0);
  tri_decode(2 * pt + 1, ti1, tj1);
  const bool twoA = (ti1 != ti0);

  const int tid = threadIdx.x, lane = tid & 63, wave = tid >> 6;
  const int half = wave >> 2;                 // 0: tile0, 1: tile1
  const int wr = (wave >> 1) & 1, wc = wave & 1;
  const int llo = lane & 15, lhi = lane >> 4;

  const int ti = half ? ti1 : ti0;
  const int tj = half ? tj1 : tj0;
  const int rowTile = ti * BM, colTile = tj * BM;
  const bool diag = (ti == tj);
  const bool posT = (tj == ti + B_ / BM);     // holds s[r][r+B] on local diag

  // staging: tile = 1024 chunks(16B); 2 rounds x 512 threads.
  // swizzle col invariant in round (64 rows == 0 mod 8).
  const int srow = tid >> 3;
  const int ssc  = ((tid & 7) ^ (srow & 7)) << 4;
  const unsigned offA0  = (unsigned)(ti0 * BM + srow) * D_ + ssc;
  const unsigned offA1  = (unsigned)(ti1 * BM + srow) * D_ + ssc;
  const unsigned offB0  = (unsigned)(tj0 * BM + srow) * D_ + ssc;
  const unsigned offB1  = (unsigned)(tj1 * BM + srow) * D_ + ssc;
  const unsigned ldsOf0 = (unsigned)tid * 16;

  // fragment bases (R17 algebra): f[ks][m] = base ^ (ks*64) + m*2048
  const unsigned baseA = (unsigned)((wr * 64 + llo) * BK + ((lhi ^ (llo & 7)) << 4));
  const unsigned baseB = (unsigned)((wc * 64 + llo) * BK + ((lhi ^ (llo & 7)) << 4));
  const char* Ab = &As[(half && twoA) ? 1 : 0][0];
  const char* Bb = &Bs[half][0];

  v4i acc[4][4] = {};

  for (int kt = 0; kt < NK; ++kt) {
    const unsigned kb = (unsigned)kt * BK;
#pragma unroll
    for (int r = 0; r < 2; ++r) {
      GLOAD_LDS16(E8 + offA0 + r * 32768 + kb, &As[0][ldsOf0 + r * 8192]);
      GLOAD_LDS16(E8 + offB0 + r * 32768 + kb, &Bs[0][ldsOf0 + r * 8192]);
      GLOAD_LDS16(E8 + offB1 + r * 32768 + kb, &Bs[1][ldsOf0 + r * 8192]);
    }
    if (twoA) {
#pragma unroll
      for (int r = 0; r < 2; ++r)
        GLOAD_LDS16(E8 + offA1 + r * 32768 + kb, &As[1][ldsOf0 + r * 8192]);
    }
    __syncthreads();   // drains vmcnt: all tiles resident
#pragma unroll
    for (int ks = 0; ks < 2; ++ks) {
      const unsigned bA = baseA ^ (ks * 64);
      const unsigned bB = baseB ^ (ks * 64);
      v4i af[4], bf[4];
#pragma unroll
      for (int m = 0; m < 4; ++m) {
        af[m] = *(const v4i*)&Ab[bA + m * 2048];
        bf[m] = *(const v4i*)&Bb[bB + m * 2048];
      }
#pragma unroll
      for (int m = 0; m < 4; ++m)
#pragma unroll
        for (int n = 0; n < 4; ++n)
          acc[m][n] = __builtin_amdgcn_mfma_i32_16x16x64_i8(af[m], bf[n],
                                                            acc[m][n], 0, 0, 0);
    }
    __syncthreads();   // protect LDS before next staging
  }

  // --- epilogue (R13-verified, per half): exp, partials, P stores ---
  // C/D layout: col = lane&15, row = (lane>>4)*4 + reg
  float* __restrict__ Prow = P + ((size_t)ti * 2 * NTILE + (size_t)tj * 2 + wc) * BM;
  float* __restrict__ Pcol = P + ((size_t)tj * 2 * NTILE + (size_t)ti * 2 + wr) * BM;
  float cs[4] = {0.f, 0.f, 0.f, 0.f};
#pragma unroll
  for (int m = 0; m < 4; ++m) {
    float rs[4] = {0.f, 0.f, 0.f, 0.f};
#pragma unroll
    for (int n = 0; n < 4; ++n) {
      int gc = colTile + wc * 64 + n * 16 + llo;
#pragma unroll
      for (int jj = 0; jj < 4; ++jj) {
        int gr = rowTile + wr * 64 + m * 16 + lhi * 4 + jj;
        float s = (float)acc[m][n][jj] * SCL;
        if (posT && gc - gr == B_) pos[gr] = s;   // unique writer
        float e = __expf(s);
        e = (diag && gr == gc) ? 0.0f : e;
        rs[jj] += e;
        cs[n]  += e;
      }
    }
#pragma unroll
    for (int jj = 0; jj < 4; ++jj) {
      float v = rs[jj];
      v += __shfl_xor(v, 1);
      v += __shfl_xor(v, 2);
      v += __shfl_xor(v, 4);
      v += __shfl_xor(v, 8);
      if (llo == 0) Prow[wr * 64 + m * 16 + lhi * 4 + jj] = v;  // slot tj*2+wc
    }
  }
  if (!diag) {
    // column sums = row sums of mirrored tile (j,i)
#pragma unroll
    for (int n = 0; n < 4; ++n) {
      float v = cs[n];
      v += __shfl_xor(v, 16);
      v += __shfl_xor(v, 32);
      if (lhi == 0) Pcol[wc * 64 + n * 16 + llo] = v;           // slot ti*2+wr
    }
  }
}

// ---------------------------------------------------------------------------
// Kernel 3: gather L[r] = sum over 128 slots of P[ti][j2][rloc];
// nll = log(L) - pos; per-block partial -> par[32].
// ---------------------------------------------------------------------------
__global__ void ntx_fin1(const float* __restrict__ P, const float* __restrict__ pos,
                         float* __restrict__ par) {
  int r = blockIdx.x * 256 + threadIdx.x;     // 32 blocks x 256 rows
  int ti = r >> 7, rloc = r & 127;
  const float* base = P + (size_t)ti * 2 * NTILE * BM + rloc;
  float s = 0.f;
#pragma unroll 16
  for (int j = 0; j < 2 * NTILE; ++j) s += base[j * BM];
  float nll = __logf(s) - pos[r & (B_ - 1)];
  float v = nll;
#pragma unroll
  for (int off = 1; off < 64; off <<= 1) v += __shfl_xor(v, off);
  __shared__ float sm[4];
  if ((threadIdx.x & 63) == 0) sm[threadIdx.x >> 6] = v;
  __syncthreads();
  if (threadIdx.x == 0) par[blockIdx.x] = sm[0] + sm[1] + sm[2] + sm[3];
}

// Kernel 4: fold 32 partials -> mean
__global__ void ntx_fin2(const float* __restrict__ par, float* __restrict__ out) {
  int t = threadIdx.x;                         // 64 threads
  float s = (t < 32) ? par[t] : 0.f;
#pragma unroll
  for (int off = 1; off < 32; off <<= 1) s += __shfl_xor(s, off);
  if (t == 0) out[0] = s * (1.0f / TB_);
}

// ---------------------------------------------------------------------------
extern "C" void kernel_launch(void* const* d_in, const int* in_sizes, int n_in,
                              void* d_out, int out_size, void* d_ws, size_t ws_size,
                              hipStream_t stream) {
  const float* e1 = (const float*)d_in[0];
  const float* e2 = (const float*)d_in[1];
  float* out = (float*)d_out;
  char*  E8  = (char*)d_ws;                                       // 4 MB i8
  float* P   = (float*)((char*)d_ws + (size_t)TB_ * D_);          // 4 MB partials
  float* pos = P + (size_t)NTILE * 2 * NTILE * BM;                // 16 KB
  float* par = pos + B_;                                          // 128 B

  ntx_prep<<<1024, 256, 0, stream>>>(e1, e2, E8);
  ntx_sim<<<NPAIR, 512, 0, stream>>>(E8, P, pos);
  ntx_fin1<<<TB_ / 256, 256, 0, stream>>>(P, pos, par);
  ntx_fin2<<<1, 64, 0, stream>>>(par, out);
}